// Round 13
// baseline (2417.610 us; speedup 1.0000x reference)
//
#include <hip/hip_runtime.h>

#define BATCH 16
#define CH    64
#define LEN   4096
#define NCODE 1024
#define NPTS  (BATCH * LEN)          // 65536
#define MT    128                    // points per block (2 per lane)
#define NW    8                      // waves per block = code slices
#define CPW   (NCODE / NW)           // 128 codes per wave
#define CG    16                     // codes per group (one s_load_dwordx16)
#define NGRP  (CPW / CG)             // 8 groups per wave
#define NPART (NPTS / MT)            // 512 partials

typedef float float2v __attribute__((ext_vector_type(2)));
typedef float float4v __attribute__((ext_vector_type(4)));

// ---------------------------------------------------------------------------
// Kernel 1 (prep): blocked-transposed codebook + w2.
//   cbt2[(G*64 + c)*16 + j] = cb[G*16 + j][c],  G in [0,64), j in [0,16)
// -> a wave sweeping c for fixed G reads CONTIGUOUS 64B lines (the 4KB-stride
//    walk of r11/r12 thrashed L2 sets: 4.15GB HBM refetch of a 256KB table).
//   w2[k] = sum_c cb[k][c]^2.
// 64 blocks x 256 thr, one 16-code group per block.
// ---------------------------------------------------------------------------
__global__ __launch_bounds__(256) void vq_prep(const float* __restrict__ cb,
                                               float* __restrict__ cbt2,
                                               float* __restrict__ w2) {
    __shared__ float tile[16][65];
    const int G = blockIdx.x;        // 16-code group
    const int t = threadIdx.x;
#pragma unroll
    for (int r = 0; r < 4; ++r) {
        int idx = r * 256 + t;       // over 16 codes x 64 ch
        int j = idx >> 6, c = idx & 63;
        tile[j][c] = cb[(size_t)(G * 16 + j) * CH + c];   // coalesced in c
    }
    __syncthreads();
#pragma unroll
    for (int r = 0; r < 4; ++r) {
        int idx = r * 256 + t;       // over 64 ch x 16 codes
        int c = idx >> 4, j = idx & 15;
        cbt2[((size_t)G * 64 + c) * 16 + j] = tile[j][c]; // contiguous writes
    }
    if (t < 16) {
        float s = 0.f;
#pragma unroll
        for (int c = 0; c < CH; ++c) s = fmaf(tile[t][c], tile[t][c], s);
        w2[G * 16 + t] = s;
    }
}

// ---------------------------------------------------------------------------
// Kernel 2: argmin — LDS-x / contiguous-scalar-codebook hybrid.
// 512 thr = 8 waves; wave = one 128-code slice; lane owns 2 points.
// Per c-step: 1 ds_read_b64 (x, conflict-free) + 1 s_load_dwordx16 from a
// SEQUENTIAL 64B stream (L2/K$-resident 256KB shared by all blocks) +
// 32 v_fmac_f32 acc,s,v. acc[2][16] static -> RA-safe (r2-6 lesson).
// Merge arrays overlaid on xs after a barrier: LDS 32KB -> 4 blocks/CU.
// ---------------------------------------------------------------------------
__global__ __launch_bounds__(512, 4) void vq_argmin(const float*  __restrict__ x,
                                                    const float*  __restrict__ cbt2,
                                                    const float*  __restrict__ w2,
                                                    float*        __restrict__ idx_out,
                                                    double*       __restrict__ partial) {
    __shared__ __attribute__((aligned(16))) float xs[CH * MT];   // 32KB, overlaid later

    const int t    = threadIdx.x;
    const int lane = t & 63;
    const int wv   = __builtin_amdgcn_readfirstlane(t >> 6);   // 0..7, scalar
    const int p0   = blockIdx.x * MT;
    const int b    = p0 >> 12;          // / LEN
    const int l0   = p0 & (LEN - 1);

    // ---- stage x tile: xs[c][l] = x[b][c][l0+l]  (coalesced float4)
#pragma unroll
    for (int r = 0; r < 4; ++r) {
        int idx = r * 512 + t;          // 2048 float4s
        int c   = idx >> 5;             // 32 float4 per row
        int l4  = idx & 31;
        *(float4v*)&xs[c * MT + 4 * l4] =
            *(const float4v*)&x[((size_t)b * CH + c) * LEN + l0 + 4 * l4];
    }
    __syncthreads();

    // ---- |x|^2 for my 2 points
    float x2a = 0.f, x2b = 0.f;
#pragma unroll
    for (int c = 0; c < CH; ++c) {
        float2v v = *(const float2v*)&xs[c * MT + 2 * lane];
        x2a = fmaf(v.x, v.x, x2a);
        x2b = fmaf(v.y, v.y, x2b);
    }

    // wave's slice: groups G = wv*NGRP .. wv*NGRP+7  (codes wv*128..wv*128+127)
    const float* __restrict__ wp  = cbt2 + (size_t)wv * NGRP * 64 * CG;  // scalar
    const float* __restrict__ w2p = w2 + wv * CPW;                        // scalar

    float best0 = 3.4e38f, best1 = 3.4e38f;
    int   bk0 = 0, bk1 = 0;

    for (int g = 0; g < NGRP; ++g) {
        const float* __restrict__ gb = wp + (size_t)g * 64 * CG;  // 4KB seq block
        float acc0[CG], acc1[CG];
#pragma unroll
        for (int j = 0; j < CG; ++j) { acc0[j] = 0.f; acc1[j] = 0.f; }

#pragma unroll
        for (int c = 0; c < CH; ++c) {
            float2v xa = *(const float2v*)&xs[c * MT + 2 * lane];  // ds_read_b64
            const float* wr = gb + c * CG;                         // s_load_dwordx16, seq
#pragma unroll
            for (int j = 0; j < CG; ++j) {
                acc0[j] = fmaf(xa.x, wr[j], acc0[j]);   // v_fmac v,s,v
                acc1[j] = fmaf(xa.y, wr[j], acc1[j]);
            }
        }

        // cost = w2[k] - 2*dot (x2 constant per point -> same argmin; strict <
        // ascending k = first-occurrence, identical to r11/r12 passing scheme)
#pragma unroll
        for (int j = 0; j < CG; ++j) {
            int   k   = g * CG + j;
            float w2k = w2p[k];
            float c0  = fmaf(-2.0f, acc0[j], w2k);
            float c1  = fmaf(-2.0f, acc1[j], w2k);
            if (c0 < best0) { best0 = c0; bk0 = k; }
            if (c1 < best1) { best1 = c1; bk1 = k; }
        }
    }
    bk0 += wv * CPW;
    bk1 += wv * CPW;

    // ---- overlay merge arrays onto xs (all xs reads are complete)
    __syncthreads();
    float*  sb0  = xs;                      // [NW*64]
    int*    sk0  = (int*)(xs + 512);        // [NW*64]
    float*  sb1  = xs + 1024;               // [NW*64]
    int*    sk1  = (int*)(xs + 1536);       // [NW*64]
    double* ssum = (double*)(xs + 2048);    // [64]

    sb0[wv * 64 + lane] = best0;  sk0[wv * 64 + lane] = bk0;
    sb1[wv * 64 + lane] = best1;  sk1[wv * 64 + lane] = bk1;
    __syncthreads();

    if (wv == 0) {
        // merge slices in ascending order (strict < keeps lowest k on ties)
#pragma unroll
        for (int s = 1; s < NW; ++s) {
            float ob0 = sb0[s * 64 + lane];
            int   ok0 = sk0[s * 64 + lane];
            if (ob0 < best0) { best0 = ob0; bk0 = ok0; }
            float ob1 = sb1[s * 64 + lane];
            int   ok1 = sk1[s * 64 + lane];
            if (ob1 < best1) { best1 = ob1; bk1 = ok1; }
        }
        float2v iv; iv.x = (float)bk0; iv.y = (float)bk1;
        *(float2v*)(idx_out + p0 + 2 * lane) = iv;
        // min d2 = x2 + (w2 - 2*dot)
        ssum[lane] = ((double)x2a + (double)best0) + ((double)x2b + (double)best1);
    }
    __syncthreads();

    if (t == 0) {
        double s = 0.0;
        for (int i = 0; i < 64; ++i) s += ssum[i];
        partial[blockIdx.x] = s;
    }
}

// ---------------------------------------------------------------------------
// Kernel 3: quant_out[b,c,l] = codebook[idx[b,l], c]  (coalesced writes)
// ---------------------------------------------------------------------------
__global__ __launch_bounds__(256) void vq_gather(const float* __restrict__ cbk,
                                                 const float* __restrict__ idx_f,
                                                 float*       __restrict__ out) {
    int t  = blockIdx.x * 256 + threadIdx.x;   // over B*C*L
    int l  = t & (LEN - 1);
    int bc = t >> 12;
    int c  = bc & (CH - 1);
    int b  = bc >> 6;
    int k  = (int)idx_f[b * LEN + l];
    out[t] = cbk[(size_t)k * CH + c];
}

// ---------------------------------------------------------------------------
// Kernel 4: final loss reduction over the NPART per-block partials.
// ---------------------------------------------------------------------------
__global__ __launch_bounds__(256) void vq_loss(const double* __restrict__ partial,
                                               float*        __restrict__ losses) {
    __shared__ double sred[256];
    double v = 0.0;
#pragma unroll
    for (int i = 0; i < NPART / 256; ++i) v += partial[threadIdx.x + 256 * i];
    sred[threadIdx.x] = v;
    __syncthreads();
    for (int s = 128; s > 0; s >>= 1) {
        if (threadIdx.x < s) sred[threadIdx.x] += sred[threadIdx.x + s];
        __syncthreads();
    }
    if (threadIdx.x == 0) {
        float loss = (float)(sred[0] / (double)((size_t)NPTS * CH));
        losses[0] = loss;   // codebook_loss
        losses[1] = loss;   // commitment_loss (same value)
    }
}

// ---------------------------------------------------------------------------
extern "C" void kernel_launch(void* const* d_in, const int* in_sizes, int n_in,
                              void* d_out, int out_size, void* d_ws, size_t ws_size,
                              hipStream_t stream) {
    const float* x  = (const float*)d_in[0];   // (B, C, L)
    const float* cb = (const float*)d_in[1];   // (K, C)
    float* out = (float*)d_out;

    // d_out layout: [quant_out (B*C*L)] [codebook_loss] [commitment_loss] [indices (B*L)]
    float* quant_out = out;
    float* losses    = out + (size_t)BATCH * CH * LEN;
    float* idx_out   = losses + 2;

    // ws: [0,8KB) double partials; [8KB,12KB) w2; [16KB,16KB+256KB) cbt2
    double* partial = (double*)d_ws;
    float*  w2      = (float*)((char*)d_ws + 8192);
    float*  cbt2    = (float*)((char*)d_ws + 16384);

    vq_prep<<<NCODE / CG, 256, 0, stream>>>(cb, cbt2, w2);
    vq_argmin<<<NPTS / MT, 512, 0, stream>>>(x, cbt2, w2, idx_out, partial);
    vq_gather<<<(BATCH * CH * LEN) / 256, 256, 0, stream>>>(cb, idx_out, quant_out);
    vq_loss<<<1, 256, 0, stream>>>(partial, losses);
}

// Round 14
// 102.567 us; speedup vs baseline: 23.5711x; 23.5711x over previous
//
#include <hip/hip_runtime.h>

#define BATCH 16
#define CH    64
#define LEN   4096
#define NCODE 1024
#define NPTS  (BATCH * LEN)   // 65536

typedef float float2v __attribute__((ext_vector_type(2)));
typedef float float4v __attribute__((ext_vector_type(4)));
typedef short short8  __attribute__((ext_vector_type(8)));
typedef float f32x16  __attribute__((ext_vector_type(16)));
typedef unsigned int uint32;

// RNE float->bf16 (bit ops: no dependence on __hip_bfloat16 ABI)
__device__ __forceinline__ unsigned short f2bf(float f) {
    uint32 u = __builtin_bit_cast(uint32, f);
    u += 0x7fffu + ((u >> 16) & 1u);
    return (unsigned short)(u >> 16);
}
__device__ __forceinline__ float bf2f(unsigned short h) {
    uint32 u = ((uint32)h) << 16;
    return __builtin_bit_cast(float, u);
}

// ---------------------------------------------------------------------------
// Kernel 1 (prep): split codebook into bf16x3 MFMA A-fragments + w2 table.
// A-frag layout (32x32x16 bf16): lane l holds A[row=l&31][k=16s+8*(l>>5)+i],
// i=0..7, for tile T (32 codes), k-slice s (4), split sigma (3):
//   cbf[(T*12 + s*3 + sigma)*512 + lane*8 + i]   (shorts)
// w2tab[(T*2 + hi)*16 + r] = w2[T*32 + (r&3)+8*(r>>2)+4*hi]  (D-layout order)
// ---------------------------------------------------------------------------
__global__ __launch_bounds__(256) void vq_prep(const float* __restrict__ cb,
                                               short* __restrict__ cbf,
                                               float* __restrict__ w2tab) {
    int k = blockIdx.x * 256 + threadIdx.x;    // 4 blocks x 256 = 1024 codes
    if (k >= NCODE) return;
    const int T = k >> 5, row = k & 31;
    float s2 = 0.f;
    for (int c = 0; c < CH; ++c) {
        float xv = cb[(size_t)k * CH + c];
        s2 = fmaf(xv, xv, s2);
        unsigned short h1 = f2bf(xv); float f1 = bf2f(h1);
        float r1 = xv - f1;                     // exact residual
        unsigned short h2 = f2bf(r1); float f2 = bf2f(h2);
        float r2 = r1 - f2;                     // exact residual
        unsigned short h3 = f2bf(r2);
        int s = c >> 4, kk = c & 15, g = kk >> 3, i = kk & 7;
        int lane = g * 32 + row;
        size_t base = ((size_t)T * 12 + s * 3) * 512 + lane * 8 + i;
        cbf[base]        = (short)h1;
        cbf[base + 512]  = (short)h2;
        cbf[base + 1024] = (short)h3;
    }
    int hi = (row >> 2) & 1, r = (row & 3) + 4 * (row >> 3);
    w2tab[((size_t)T * 2 + hi) * 16 + r] = s2;
}

// ---------------------------------------------------------------------------
// Kernel 2: MFMA argmin. Grid = 512 pt-groups x 4 code-quarters.
// Block: 512 thr = 8 waves; LDS = codebook-quarter frags (96KB) + x tile
// (128 pts fp32, 32KB) = 128KB -> 1 block/CU -> RA budget ~256 VGPR (no
// spill; r11-13's 0.3-4GB scratch traffic came from the 64-VGPR/8-wave RA
// target when LDS was small). Wave = 1 pt-tile (32 pts) x 4 code-tiles.
// Per 32x32 tile: 12 ds_read_b128 (A frags) + 24 MFMA (6 split-terms x
// 4 k-slices) accumulating dot in fp32 from 0; cost = fmaf(-2,dot,w2).
// bf16x3 dropped-term error ~1e-6 << fp32-reorder noise already tolerated.
// ---------------------------------------------------------------------------
__global__ __launch_bounds__(512, 2) void vq_argmin(const float*  __restrict__ x,
                                                    const short*  __restrict__ cbf,
                                                    const float*  __restrict__ w2tab,
                                                    float2v*      __restrict__ cand) {
    __shared__ __attribute__((aligned(16))) short cbq[49152];   // 96KB
    __shared__ __attribute__((aligned(16))) float xs[CH * 128]; // 32KB

    const int t  = threadIdx.x;
    const int bi = blockIdx.x;
    const int pg = bi >> 2;        // point group (128 pts)
    const int cq = bi & 3;         // code quarter (256 codes = 8 tiles)
    const int p0 = pg * 128;
    const int b  = p0 >> 12;
    const int l0 = p0 & (LEN - 1);

    // stage codebook quarter (6144 x 16B, coalesced)
    {
        const float4v* src = (const float4v*)(cbf + (size_t)cq * 49152);
        float4v* dst = (float4v*)cbq;
#pragma unroll
        for (int it = 0; it < 12; ++it) dst[it * 512 + t] = src[it * 512 + t];
    }
    // stage x tile: xs[c][pt] (2048 x 16B, coalesced)
    {
#pragma unroll
        for (int it = 0; it < 4; ++it) {
            int fi = it * 512 + t;
            int c = fi >> 5, p4 = fi & 31;
            *(float4v*)&xs[c * 128 + 4 * p4] =
                *(const float4v*)&x[((size_t)b * CH + c) * LEN + l0 + 4 * p4];
        }
    }
    __syncthreads();

    const int l   = t & 63;
    const int w   = t >> 6;               // wave 0..7
    const int ptl = (w & 3) * 32 + (l & 31);   // local point (B col = l&31)
    const int g   = l >> 5;               // k-half group
    const int h2  = w >> 2;               // code half within quarter

    // build B-frags (x splits), loop-invariant across all code tiles
    short8 B1[4], B2[4], B3[4];
#pragma unroll
    for (int s = 0; s < 4; ++s) {
#pragma unroll
        for (int i = 0; i < 8; ++i) {
            int c = s * 16 + g * 8 + i;    // same k-mapping as A frags
            float xv = xs[c * 128 + ptl];
            unsigned short h1v = f2bf(xv); float f1 = bf2f(h1v);
            float r1 = xv - f1;
            unsigned short h2v = f2bf(r1); float f2 = bf2f(h2v);
            float r2 = r1 - f2;
            unsigned short h3v = f2bf(r2);
            B1[s][i] = (short)h1v; B2[s][i] = (short)h2v; B3[s][i] = (short)h3v;
        }
    }

    float bestc = 3.4e38f;
    int   bestk = 0;

#pragma unroll
    for (int tt = 0; tt < 4; ++tt) {       // this wave's 4 code tiles, ascending
        const int tl = h2 * 4 + tt;
        f32x16 acc = {0.f,0.f,0.f,0.f,0.f,0.f,0.f,0.f,
                      0.f,0.f,0.f,0.f,0.f,0.f,0.f,0.f};
#pragma unroll
        for (int s = 0; s < 4; ++s) {
            const int fb = (tl * 12 + s * 3) * 512 + l * 8;
            short8 A1 = *(const short8*)&cbq[fb];
            short8 A2 = *(const short8*)&cbq[fb + 512];
            short8 A3 = *(const short8*)&cbq[fb + 1024];
            // 6 split terms: 1, 2^-8, 2^-8, 2^-16, 2^-16, 2^-16
            acc = __builtin_amdgcn_mfma_f32_32x32x16_bf16(A1, B1[s], acc, 0, 0, 0);
            acc = __builtin_amdgcn_mfma_f32_32x32x16_bf16(A1, B2[s], acc, 0, 0, 0);
            acc = __builtin_amdgcn_mfma_f32_32x32x16_bf16(A2, B1[s], acc, 0, 0, 0);
            acc = __builtin_amdgcn_mfma_f32_32x32x16_bf16(A1, B3[s], acc, 0, 0, 0);
            acc = __builtin_amdgcn_mfma_f32_32x32x16_bf16(A3, B1[s], acc, 0, 0, 0);
            acc = __builtin_amdgcn_mfma_f32_32x32x16_bf16(A2, B2[s], acc, 0, 0, 0);
        }
        const int Tg = cq * 8 + tl;
        const float4v* wt = (const float4v*)(w2tab + ((size_t)Tg * 2 + g) * 16);
        float4v w0 = wt[0], w1 = wt[1], w2v = wt[2], w3 = wt[3];
        float wr[16] = {w0.x, w0.y, w0.z, w0.w, w1.x, w1.y, w1.z, w1.w,
                        w2v.x, w2v.y, w2v.z, w2v.w, w3.x, w3.y, w3.z, w3.w};
#pragma unroll
        for (int r = 0; r < 16; ++r) {     // rows ascend with r -> ascending k
            float cost = fmaf(-2.0f, acc[r], wr[r]);
            int kg = Tg * 32 + (r & 3) + 8 * (r >> 2) + 4 * g;
            if (cost < bestc) { bestc = cost; bestk = kg; }   // strict <
        }
    }

    // reduce the two lane-halves (same point, interleaved code rows)
    {
        float ob = __shfl_xor(bestc, 32, 64);
        int   ok = __shfl_xor(bestk, 32, 64);
        if (ob < bestc || (ob == bestc && ok < bestk)) { bestc = ob; bestk = ok; }
    }
    if (g == 0) {
        float2v cv; cv.x = bestc; cv.y = (float)bestk;
        cand[(size_t)(p0 + ptl) * 8 + cq * 2 + h2] = cv;   // cand j ~ ascending k
    }
}

// ---------------------------------------------------------------------------
// Kernel 3 (merge): per point pick best of 8 candidates (ascending-k order,
// strict < + smaller-k tie) -> idx; compute x2; accumulate loss partials.
// ---------------------------------------------------------------------------
__global__ __launch_bounds__(256) void vq_merge(const float*   __restrict__ x,
                                                const float2v* __restrict__ cand,
                                                float*         __restrict__ idx_out,
                                                double*        __restrict__ partial) {
    __shared__ double sred[256];
    const int t  = threadIdx.x;
    const int pt = blockIdx.x * 256 + t;
    const int b  = pt >> 12, l = pt & (LEN - 1);

    float bestc = 3.4e38f; int bestk = 0;
#pragma unroll
    for (int j = 0; j < 8; ++j) {
        float2v c = cand[(size_t)pt * 8 + j];
        float sc = c.x; int k = (int)c.y;
        if (sc < bestc || (sc == bestc && k < bestk)) { bestc = sc; bestk = k; }
    }
    float x2 = 0.f;
    for (int c = 0; c < CH; ++c) {
        float v = x[((size_t)b * CH + c) * LEN + l];   // coalesced across threads
        x2 = fmaf(v, v, x2);
    }
    idx_out[pt] = (float)bestk;
    sred[t] = (double)x2 + (double)bestc;   // min d2 = x2 + (w2 - 2 dot)
    __syncthreads();
    for (int s = 128; s > 0; s >>= 1) {
        if (t < s) sred[t] += sred[t + s];
        __syncthreads();
    }
    if (t == 0) partial[blockIdx.x] = sred[0];
}

// ---------------------------------------------------------------------------
// Kernel 4: quant_out[b,c,l] = codebook[idx[b,l], c]  (coalesced writes)
// ---------------------------------------------------------------------------
__global__ __launch_bounds__(256) void vq_gather(const float* __restrict__ cbk,
                                                 const float* __restrict__ idx_f,
                                                 float*       __restrict__ out) {
    int t  = blockIdx.x * 256 + threadIdx.x;   // over B*C*L
    int l  = t & (LEN - 1);
    int bc = t >> 12;
    int c  = bc & (CH - 1);
    int b  = bc >> 6;
    int k  = (int)idx_f[b * LEN + l];
    out[t] = cbk[(size_t)k * CH + c];
}

// ---------------------------------------------------------------------------
// Kernel 5: final loss reduction over 256 per-block partials.
// ---------------------------------------------------------------------------
__global__ __launch_bounds__(256) void vq_loss(const double* __restrict__ partial,
                                               float*        __restrict__ losses) {
    __shared__ double sred[256];
    sred[threadIdx.x] = partial[threadIdx.x];
    __syncthreads();
    for (int s = 128; s > 0; s >>= 1) {
        if (threadIdx.x < s) sred[threadIdx.x] += sred[threadIdx.x + s];
        __syncthreads();
    }
    if (threadIdx.x == 0) {
        float loss = (float)(sred[0] / (double)((size_t)NPTS * CH));
        losses[0] = loss;   // codebook_loss
        losses[1] = loss;   // commitment_loss (same value)
    }
}

// ---------------------------------------------------------------------------
extern "C" void kernel_launch(void* const* d_in, const int* in_sizes, int n_in,
                              void* d_out, int out_size, void* d_ws, size_t ws_size,
                              hipStream_t stream) {
    const float* x  = (const float*)d_in[0];   // (B, C, L)
    const float* cb = (const float*)d_in[1];   // (K, C)
    float* out = (float*)d_out;

    // d_out: [quant_out (B*C*L)] [codebook_loss] [commitment_loss] [indices (B*L)]
    float* quant_out = out;
    float* losses    = out + (size_t)BATCH * CH * LEN;
    float* idx_out   = losses + 2;

    // ws: [0,2KB) partials(256 dbl); [4KB,8KB) w2tab; [16KB,400KB) cbf splits;
    //     [512KB,4.5MB) cand[65536][8] float2
    double*  partial = (double*)d_ws;
    float*   w2tab   = (float*)((char*)d_ws + 4096);
    short*   cbf     = (short*)((char*)d_ws + 16384);
    float2v* cand    = (float2v*)((char*)d_ws + 524288);

    vq_prep<<<NCODE / 256, 256, 0, stream>>>(cb, cbf, w2tab);
    vq_argmin<<<(NPTS / 128) * 4, 512, 0, stream>>>(x, cbf, w2tab, cand);
    vq_merge<<<NPTS / 256, 256, 0, stream>>>(x, cand, idx_out, partial);
    vq_gather<<<(BATCH * CH * LEN) / 256, 256, 0, stream>>>(cb, idx_out, quant_out);
    vq_loss<<<1, 256, 0, stream>>>(partial, losses);
}

// Round 15
// 89.033 us; speedup vs baseline: 27.1540x; 1.1520x over previous
//
#include <hip/hip_runtime.h>

#define BATCH 16
#define CH    64
#define LEN   4096
#define NCODE 1024
#define NPTS  (BATCH * LEN)   // 65536
#define NPART 512             // argmin blocks

typedef float float2v __attribute__((ext_vector_type(2)));
typedef float float4v __attribute__((ext_vector_type(4)));
typedef short short8  __attribute__((ext_vector_type(8)));
typedef float f32x16  __attribute__((ext_vector_type(16)));
typedef unsigned int uint32;

// RNE float->bf16 (bit ops: no dependence on __hip_bfloat16 ABI)
__device__ __forceinline__ unsigned short f2bf(float f) {
    uint32 u = __builtin_bit_cast(uint32, f);
    u += 0x7fffu + ((u >> 16) & 1u);
    return (unsigned short)(u >> 16);
}
__device__ __forceinline__ float bf2f(unsigned short h) {
    uint32 u = ((uint32)h) << 16;
    return __builtin_bit_cast(float, u);
}

// ---------------------------------------------------------------------------
// Kernel 1 (prep): split codebook into bf16x3 MFMA A-fragments + w2 table.
// A-frag layout (32x32x16 bf16): lane l holds A[row=l&31][k=16s+8*(l>>5)+i],
//   cbf[(T*12 + s*3 + sigma)*512 + lane*8 + i]   (shorts)
// w2tab[(T*2 + hi)*16 + r] = w2[T*32 + (r&3)+8*(r>>2)+4*hi]  (D-layout order)
// (identical to the r14 passing version)
// ---------------------------------------------------------------------------
__global__ __launch_bounds__(256) void vq_prep(const float* __restrict__ cb,
                                               short* __restrict__ cbf,
                                               float* __restrict__ w2tab) {
    int k = blockIdx.x * 256 + threadIdx.x;    // 4 blocks x 256 = 1024 codes
    if (k >= NCODE) return;
    const int T = k >> 5, row = k & 31;
    float s2 = 0.f;
    for (int c = 0; c < CH; ++c) {
        float xv = cb[(size_t)k * CH + c];
        s2 = fmaf(xv, xv, s2);
        unsigned short h1 = f2bf(xv); float f1 = bf2f(h1);
        float r1 = xv - f1;                     // exact residual
        unsigned short h2 = f2bf(r1); float f2 = bf2f(h2);
        float r2 = r1 - f2;                     // exact residual
        unsigned short h3 = f2bf(r2);
        int s = c >> 4, kk = c & 15, g = kk >> 3, i = kk & 7;
        int lane = g * 32 + row;
        size_t base = ((size_t)T * 12 + s * 3) * 512 + lane * 8 + i;
        cbf[base]        = (short)h1;
        cbf[base + 512]  = (short)h2;
        cbf[base + 1024] = (short)h3;
    }
    int hi = (row >> 2) & 1, r = (row & 3) + 4 * (row >> 3);
    w2tab[((size_t)T * 2 + hi) * 16 + r] = s2;
}

// per-tile epilogue: cost = w2 - 2*dot, running argmin (rows ascend in k).
__device__ __forceinline__ void epi(const f32x16& acc, int Tg, int g,
                                    float& bestc, int& bestk,
                                    const float* __restrict__ w2tab) {
    const float4v* wt = (const float4v*)(w2tab + ((size_t)Tg * 2 + g) * 16);
    float4v w0 = wt[0], w1 = wt[1], w2v = wt[2], w3 = wt[3];
    float wr[16] = {w0.x, w0.y, w0.z, w0.w, w1.x, w1.y, w1.z, w1.w,
                    w2v.x, w2v.y, w2v.z, w2v.w, w3.x, w3.y, w3.z, w3.w};
    int kbase = Tg * 32 + 4 * g;
#pragma unroll
    for (int r = 0; r < 16; ++r) {
        float cost = fmaf(-2.0f, acc[r], wr[r]);
        int kg = kbase + (r & 3) + 8 * (r >> 2);   // ascending in r
        if (cost < bestc) { bestc = cost; bestk = kg; }   // strict <
    }
}

// ---------------------------------------------------------------------------
// Kernel 2: MFMA argmin — one block owns ALL 1024 codes for 128 points.
// 512 thr = 8 waves = 4 pt-subtiles x 2 code-halves. x staged once, bf16x3
// B-frags built ONCE (r14 rebuilt them 4x = dominant VALU). Codebook swept
// as 8 x 48KB eighths through a double-buffered LDS pair: issue next-eighth
// loads -> compute current (2 interleaved MFMA chains) -> barrier ->
// ds_write -> barrier (T14). In-kernel merge kills cand buffer + merge
// kernel. LDS 131KB -> 1 block/CU -> relaxed RA (r13 lesson, no spill).
// ---------------------------------------------------------------------------
__global__ __launch_bounds__(512, 2) void vq_argmin(const float*  __restrict__ x,
                                                    const short*  __restrict__ cbf,
                                                    const float*  __restrict__ w2tab,
                                                    float*        __restrict__ idx_out,
                                                    double*       __restrict__ partial) {
    __shared__ __attribute__((aligned(16))) short cbb[2][24576];  // 2 x 48KB
    __shared__ __attribute__((aligned(16))) float xs[CH * 128];   // 32KB
    __shared__ float  smc[8][32];
    __shared__ int    smk[8][32];
    __shared__ double sds[128];

    const int t   = threadIdx.x;
    const int l   = t & 63;
    const int w   = __builtin_amdgcn_readfirstlane(t >> 6);  // 0..7
    const int h2  = w >> 2;                 // code half
    const int ptl = (w & 3) * 32 + (l & 31);
    const int g   = l >> 5;                 // k-half group
    const int p0  = blockIdx.x * 128;
    const int b   = p0 >> 12;
    const int l0  = p0 & (LEN - 1);

    // ---- prologue staging: x tile (4 chunks) + eighth 0 (6 chunks)
    {
        float4v xr[4], c0[6];
#pragma unroll
        for (int it = 0; it < 4; ++it) {
            int fi = it * 512 + t, c = fi >> 5, p4 = fi & 31;
            xr[it] = *(const float4v*)&x[((size_t)b * CH + c) * LEN + l0 + 4 * p4];
        }
        const float4v* cs = (const float4v*)cbf;
#pragma unroll
        for (int it = 0; it < 6; ++it) c0[it] = cs[it * 512 + t];
#pragma unroll
        for (int it = 0; it < 4; ++it) {
            int fi = it * 512 + t, c = fi >> 5, p4 = fi & 31;
            *(float4v*)&xs[c * 128 + 4 * p4] = xr[it];
        }
        float4v* d0 = (float4v*)cbb[0];
#pragma unroll
        for (int it = 0; it < 6; ++it) d0[it * 512 + t] = c0[it];
    }
    __syncthreads();

    // ---- build B-frags (x splits) ONCE + x2 partial over my 32 channels
    short8 B1[4], B2[4], B3[4];
    float x2p = 0.f;
#pragma unroll
    for (int s = 0; s < 4; ++s) {
#pragma unroll
        for (int i = 0; i < 8; ++i) {
            int c = s * 16 + g * 8 + i;     // same k-mapping as A frags
            float xv = xs[c * 128 + ptl];
            x2p = fmaf(xv, xv, x2p);
            unsigned short h1v = f2bf(xv); float f1 = bf2f(h1v);
            float r1 = xv - f1;
            unsigned short h2v = f2bf(r1); float f2 = bf2f(h2v);
            float r2 = r1 - f2;
            unsigned short h3v = f2bf(r2);
            B1[s][i] = (short)h1v; B2[s][i] = (short)h2v; B3[s][i] = (short)h3v;
        }
    }
    const float x2 = x2p + __shfl_xor(x2p, 32, 64);   // lane pairs share point

    float bestc = 3.4e38f;
    int   bestk = 0;

    // ---- sweep 8 eighths (128 codes each), double-buffered
    for (int e = 0; e < 8; ++e) {
        float4v nb[6];
        if (e < 7) {   // issue next-eighth loads; latency hides under MFMA
            const float4v* cs = (const float4v*)(cbf + (size_t)(e + 1) * 24576);
#pragma unroll
            for (int it = 0; it < 6; ++it) nb[it] = cs[it * 512 + t];
        }

        const short* bp = cbb[e & 1];
        f32x16 accA = {0.f,0.f,0.f,0.f,0.f,0.f,0.f,0.f,
                       0.f,0.f,0.f,0.f,0.f,0.f,0.f,0.f};
        f32x16 accB = accA;
        const int fbA0 = (h2 * 2) * 12 * 512, fbB0 = (h2 * 2 + 1) * 12 * 512;
#pragma unroll
        for (int s = 0; s < 4; ++s) {
            int fa = fbA0 + s * 3 * 512 + l * 8;
            int fb = fbB0 + s * 3 * 512 + l * 8;
            short8 A1a = *(const short8*)&bp[fa];
            short8 A2a = *(const short8*)&bp[fa + 512];
            short8 A3a = *(const short8*)&bp[fa + 1024];
            short8 A1b = *(const short8*)&bp[fb];
            short8 A2b = *(const short8*)&bp[fb + 512];
            short8 A3b = *(const short8*)&bp[fb + 1024];
            // 6 split terms, two independent accumulator chains (A/B tiles)
            accA = __builtin_amdgcn_mfma_f32_32x32x16_bf16(A1a, B1[s], accA, 0, 0, 0);
            accB = __builtin_amdgcn_mfma_f32_32x32x16_bf16(A1b, B1[s], accB, 0, 0, 0);
            accA = __builtin_amdgcn_mfma_f32_32x32x16_bf16(A1a, B2[s], accA, 0, 0, 0);
            accB = __builtin_amdgcn_mfma_f32_32x32x16_bf16(A1b, B2[s], accB, 0, 0, 0);
            accA = __builtin_amdgcn_mfma_f32_32x32x16_bf16(A2a, B1[s], accA, 0, 0, 0);
            accB = __builtin_amdgcn_mfma_f32_32x32x16_bf16(A2b, B1[s], accB, 0, 0, 0);
            accA = __builtin_amdgcn_mfma_f32_32x32x16_bf16(A1a, B3[s], accA, 0, 0, 0);
            accB = __builtin_amdgcn_mfma_f32_32x32x16_bf16(A1b, B3[s], accB, 0, 0, 0);
            accA = __builtin_amdgcn_mfma_f32_32x32x16_bf16(A3a, B1[s], accA, 0, 0, 0);
            accB = __builtin_amdgcn_mfma_f32_32x32x16_bf16(A3b, B1[s], accB, 0, 0, 0);
            accA = __builtin_amdgcn_mfma_f32_32x32x16_bf16(A2a, B2[s], accA, 0, 0, 0);
            accB = __builtin_amdgcn_mfma_f32_32x32x16_bf16(A2b, B2[s], accB, 0, 0, 0);
        }
        epi(accA, e * 4 + h2 * 2,     g, bestc, bestk, w2tab);
        epi(accB, e * 4 + h2 * 2 + 1, g, bestc, bestk, w2tab);

        __syncthreads();            // all waves done reading cbb[e&1] & (e+1)&1
        if (e < 7) {
            float4v* dn = (float4v*)cbb[(e + 1) & 1];
#pragma unroll
            for (int it = 0; it < 6; ++it) dn[it * 512 + t] = nb[it];
            __syncthreads();        // next eighth visible
        }
    }

    // ---- merge g-halves within wave (explicit smaller-k tie-break)
    {
        float ob = __shfl_xor(bestc, 32, 64);
        int   ok = __shfl_xor(bestk, 32, 64);
        if (ob < bestc || (ob == bestc && ok < bestk)) { bestc = ob; bestk = ok; }
    }
    // ---- merge the two code-half waves per point via LDS
    if (l < 32) { smc[w][l] = bestc; smk[w][l] = bestk; }
    __syncthreads();
    if (w < 4 && l < 32) {
        float ob = smc[w + 4][l];
        int   ok = smk[w + 4][l];
        if (ob < bestc || (ob == bestc && ok < bestk)) { bestc = ob; bestk = ok; }
        idx_out[p0 + w * 32 + l] = (float)bestk;
        sds[w * 32 + l] = (double)x2 + (double)bestc;   // min d2 = x2 + (w2-2dot)
    }
    __syncthreads();
    if (t == 0) {
        double s = 0.0;
        for (int i = 0; i < 128; ++i) s += sds[i];
        partial[blockIdx.x] = s;
    }
}

// ---------------------------------------------------------------------------
// Kernel 3: quant_out[b,c,l] = codebook[idx[b,l], c]  (coalesced writes)
// ---------------------------------------------------------------------------
__global__ __launch_bounds__(256) void vq_gather(const float* __restrict__ cbk,
                                                 const float* __restrict__ idx_f,
                                                 float*       __restrict__ out) {
    int t  = blockIdx.x * 256 + threadIdx.x;   // over B*C*L
    int l  = t & (LEN - 1);
    int bc = t >> 12;
    int c  = bc & (CH - 1);
    int b  = bc >> 6;
    int k  = (int)idx_f[b * LEN + l];
    out[t] = cbk[(size_t)k * CH + c];
}

// ---------------------------------------------------------------------------
// Kernel 4: final loss reduction over NPART per-block partials.
// ---------------------------------------------------------------------------
__global__ __launch_bounds__(256) void vq_loss(const double* __restrict__ partial,
                                               float*        __restrict__ losses) {
    __shared__ double sred[256];
    double v = 0.0;
#pragma unroll
    for (int i = 0; i < NPART / 256; ++i) v += partial[threadIdx.x + 256 * i];
    sred[threadIdx.x] = v;
    __syncthreads();
    for (int s = 128; s > 0; s >>= 1) {
        if (threadIdx.x < s) sred[threadIdx.x] += sred[threadIdx.x + s];
        __syncthreads();
    }
    if (threadIdx.x == 0) {
        float loss = (float)(sred[0] / (double)((size_t)NPTS * CH));
        losses[0] = loss;   // codebook_loss
        losses[1] = loss;   // commitment_loss (same value)
    }
}

// ---------------------------------------------------------------------------
extern "C" void kernel_launch(void* const* d_in, const int* in_sizes, int n_in,
                              void* d_out, int out_size, void* d_ws, size_t ws_size,
                              hipStream_t stream) {
    const float* x  = (const float*)d_in[0];   // (B, C, L)
    const float* cb = (const float*)d_in[1];   // (K, C)
    float* out = (float*)d_out;

    // d_out: [quant_out (B*C*L)] [codebook_loss] [commitment_loss] [indices (B*L)]
    float* quant_out = out;
    float* losses    = out + (size_t)BATCH * CH * LEN;
    float* idx_out   = losses + 2;

    // ws: [0,4KB) partials(512 dbl); [4KB,8KB) w2tab; [16KB,~400KB) cbf splits
    double* partial = (double*)d_ws;
    float*  w2tab   = (float*)((char*)d_ws + 4096);
    short*  cbf     = (short*)((char*)d_ws + 16384);

    vq_prep<<<NCODE / 256, 256, 0, stream>>>(cb, cbf, w2tab);
    vq_argmin<<<NPTS / 128, 512, 0, stream>>>(x, cbf, w2tab, idx_out, partial);
    vq_gather<<<(BATCH * CH * LEN) / 256, 256, 0, stream>>>(cb, idx_out, quant_out);
    vq_loss<<<1, 256, 0, stream>>>(partial, losses);
}

// Round 16
// 86.877 us; speedup vs baseline: 27.8279x; 1.0248x over previous
//
#include <hip/hip_runtime.h>

#define BATCH 16
#define CH    64
#define LEN   4096
#define NCODE 1024
#define NPTS  (BATCH * LEN)   // 65536
#define NPART 512             // argmin blocks

typedef float float2v __attribute__((ext_vector_type(2)));
typedef float float4v __attribute__((ext_vector_type(4)));
typedef short short8  __attribute__((ext_vector_type(8)));
typedef float f32x16  __attribute__((ext_vector_type(16)));
typedef unsigned int uint32;

// RNE float->bf16 (bit ops: no dependence on __hip_bfloat16 ABI)
__device__ __forceinline__ unsigned short f2bf(float f) {
    uint32 u = __builtin_bit_cast(uint32, f);
    u += 0x7fffu + ((u >> 16) & 1u);
    return (unsigned short)(u >> 16);
}
__device__ __forceinline__ float bf2f(unsigned short h) {
    uint32 u = ((uint32)h) << 16;
    return __builtin_bit_cast(float, u);
}

// ---------------------------------------------------------------------------
// Kernel 1 (prep): split codebook into bf16x3 MFMA A-fragments + w2 table.
// A-frag layout (32x32x16 bf16): lane l holds A[row=l&31][k=16s+8*(l>>5)+i],
//   cbf[(T*12 + s*3 + sigma)*512 + lane*8 + i]   (shorts)
// w2tab[(T*2 + hi)*16 + r] = w2[T*32 + (r&3)+8*(r>>2)+4*hi]  (D-layout order)
// (identical to the r14/r15 passing version)
// ---------------------------------------------------------------------------
__global__ __launch_bounds__(256) void vq_prep(const float* __restrict__ cb,
                                               short* __restrict__ cbf,
                                               float* __restrict__ w2tab) {
    int k = blockIdx.x * 256 + threadIdx.x;    // 4 blocks x 256 = 1024 codes
    if (k >= NCODE) return;
    const int T = k >> 5, row = k & 31;
    float s2 = 0.f;
    for (int c = 0; c < CH; ++c) {
        float xv = cb[(size_t)k * CH + c];
        s2 = fmaf(xv, xv, s2);
        unsigned short h1 = f2bf(xv); float f1 = bf2f(h1);
        float r1 = xv - f1;                     // exact residual
        unsigned short h2 = f2bf(r1); float f2 = bf2f(h2);
        float r2 = r1 - f2;                     // exact residual
        unsigned short h3 = f2bf(r2);
        int s = c >> 4, kk = c & 15, g = kk >> 3, i = kk & 7;
        int lane = g * 32 + row;
        size_t base = ((size_t)T * 12 + s * 3) * 512 + lane * 8 + i;
        cbf[base]        = (short)h1;
        cbf[base + 512]  = (short)h2;
        cbf[base + 1024] = (short)h3;
    }
    int hi = (row >> 2) & 1, r = (row & 3) + 4 * (row >> 3);
    w2tab[((size_t)T * 2 + hi) * 16 + r] = s2;
}

// per-tile epilogue: cost = w2 - 2*dot, running argmin (rows ascend in k).
__device__ __forceinline__ void epi(const f32x16& acc, int Tg, int g,
                                    float& bestc, int& bestk,
                                    const float* __restrict__ w2tab) {
    const float4v* wt = (const float4v*)(w2tab + ((size_t)Tg * 2 + g) * 16);
    float4v w0 = wt[0], w1 = wt[1], w2v = wt[2], w3 = wt[3];
    float wr[16] = {w0.x, w0.y, w0.z, w0.w, w1.x, w1.y, w1.z, w1.w,
                    w2v.x, w2v.y, w2v.z, w2v.w, w3.x, w3.y, w3.z, w3.w};
    int kbase = Tg * 32 + 4 * g;
#pragma unroll
    for (int r = 0; r < 16; ++r) {
        float cost = fmaf(-2.0f, acc[r], wr[r]);
        int kg = kbase + (r & 3) + 8 * (r >> 2);   // ascending in r
        if (cost < bestc) { bestc = cost; bestk = kg; }   // strict <
    }
}

// ---------------------------------------------------------------------------
// Kernel 2: MFMA argmin — direct-global codebook (no LDS staging, no in-loop
// barriers). cbf is 384KB read-only shared by all blocks -> L2-resident; each
// wave streams its A-frags via lane-coalesced global_load_dwordx4, which the
// compiler software-pipelines across tiles (load-ahead is now a feature, not
// the r2-6 bug). LDS = x tile (32KB) + merge (3KB) -> occupancy wave-slot
// bound; amdgpu_waves_per_eu(4,4) pins RA budget at 128 VGPR (no spill, r13
// lesson) -> 4 waves/SIMD, 2 blocks/CU — 2x r15's latency hiding; the 16
// barriers/sweep of r15's double-buffer are gone.
// 512 thr = 8 waves = 4 pt-subtiles x 2 code-halves; wave sweeps 16 tiles.
// #pragma unroll 2 -> two independent acc chains + cross-tile prefetch.
// ---------------------------------------------------------------------------
__global__ void __launch_bounds__(512)
__attribute__((amdgpu_waves_per_eu(4, 4)))
vq_argmin(const float*  __restrict__ x,
          const short*  __restrict__ cbf,
          const float*  __restrict__ w2tab,
          float*        __restrict__ idx_out,
          double*       __restrict__ partial) {
    __shared__ __attribute__((aligned(16))) float xs[CH * 128];   // 32KB
    __shared__ float  smc[8][32];
    __shared__ int    smk[8][32];
    __shared__ double sds[128];

    const int t   = threadIdx.x;
    const int l   = t & 63;
    const int w   = __builtin_amdgcn_readfirstlane(t >> 6);  // 0..7
    const int h2  = w >> 2;                 // code half
    const int ptl = (w & 3) * 32 + (l & 31);
    const int g   = l >> 5;                 // k-half group
    const int p0  = blockIdx.x * 128;
    const int b   = p0 >> 12;
    const int l0  = p0 & (LEN - 1);

    // ---- stage x tile: xs[c][pt] (coalesced float4)
#pragma unroll
    for (int it = 0; it < 4; ++it) {
        int fi = it * 512 + t, c = fi >> 5, p4 = fi & 31;
        *(float4v*)&xs[c * 128 + 4 * p4] =
            *(const float4v*)&x[((size_t)b * CH + c) * LEN + l0 + 4 * p4];
    }
    __syncthreads();

    // ---- build B-frags (x splits) ONCE + x2 partial over my 32 channels
    short8 B1[4], B2[4], B3[4];
    float x2p = 0.f;
#pragma unroll
    for (int s = 0; s < 4; ++s) {
#pragma unroll
        for (int i = 0; i < 8; ++i) {
            int c = s * 16 + g * 8 + i;     // same k-mapping as A frags
            float xv = xs[c * 128 + ptl];
            x2p = fmaf(xv, xv, x2p);
            unsigned short h1v = f2bf(xv); float f1 = bf2f(h1v);
            float r1 = xv - f1;
            unsigned short h2v = f2bf(r1); float f2 = bf2f(h2v);
            float r2 = r1 - f2;
            unsigned short h3v = f2bf(r2);
            B1[s][i] = (short)h1v; B2[s][i] = (short)h2v; B3[s][i] = (short)h3v;
        }
    }
    const float x2 = x2p + __shfl_xor(x2p, 32, 64);   // lane pairs share point

    float bestc = 3.4e38f;
    int   bestk = 0;

    // ---- sweep this wave's 16 code tiles (512 codes), ascending k
#pragma unroll 2
    for (int tt = 0; tt < 16; ++tt) {
        const int tl = h2 * 16 + tt;
        const short* fp = cbf + ((size_t)tl * 12) * 512 + l * 8;
        f32x16 acc = {0.f,0.f,0.f,0.f,0.f,0.f,0.f,0.f,
                      0.f,0.f,0.f,0.f,0.f,0.f,0.f,0.f};
#pragma unroll
        for (int s = 0; s < 4; ++s) {
            const short* fb = fp + (s * 3) * 512;
            short8 A1 = *(const short8*)(fb);          // global_load_dwordx4
            short8 A2 = *(const short8*)(fb + 512);
            short8 A3 = *(const short8*)(fb + 1024);
            // 6 split terms: 1, 2^-8, 2^-8, 2^-16, 2^-16, 2^-16
            acc = __builtin_amdgcn_mfma_f32_32x32x16_bf16(A1, B1[s], acc, 0, 0, 0);
            acc = __builtin_amdgcn_mfma_f32_32x32x16_bf16(A1, B2[s], acc, 0, 0, 0);
            acc = __builtin_amdgcn_mfma_f32_32x32x16_bf16(A2, B1[s], acc, 0, 0, 0);
            acc = __builtin_amdgcn_mfma_f32_32x32x16_bf16(A1, B3[s], acc, 0, 0, 0);
            acc = __builtin_amdgcn_mfma_f32_32x32x16_bf16(A3, B1[s], acc, 0, 0, 0);
            acc = __builtin_amdgcn_mfma_f32_32x32x16_bf16(A2, B2[s], acc, 0, 0, 0);
        }
        epi(acc, tl, g, bestc, bestk, w2tab);
    }

    // ---- merge g-halves within wave (explicit smaller-k tie-break)
    {
        float ob = __shfl_xor(bestc, 32, 64);
        int   ok = __shfl_xor(bestk, 32, 64);
        if (ob < bestc || (ob == bestc && ok < bestk)) { bestc = ob; bestk = ok; }
    }
    // ---- merge the two code-half waves per point via LDS
    if (l < 32) { smc[w][l] = bestc; smk[w][l] = bestk; }
    __syncthreads();
    if (w < 4 && l < 32) {
        float ob = smc[w + 4][l];
        int   ok = smk[w + 4][l];
        if (ob < bestc || (ob == bestc && ok < bestk)) { bestc = ob; bestk = ok; }
        idx_out[p0 + w * 32 + l] = (float)bestk;
        sds[w * 32 + l] = (double)x2 + (double)bestc;   // min d2 = x2 + (w2-2dot)
    }
    __syncthreads();
    if (t == 0) {
        double s = 0.0;
        for (int i = 0; i < 128; ++i) s += sds[i];
        partial[blockIdx.x] = s;
    }
}

// ---------------------------------------------------------------------------
// Kernel 3: quant_out[b,c,l] = codebook[idx[b,l], c]  (coalesced writes)
// ---------------------------------------------------------------------------
__global__ __launch_bounds__(256) void vq_gather(const float* __restrict__ cbk,
                                                 const float* __restrict__ idx_f,
                                                 float*       __restrict__ out) {
    int t  = blockIdx.x * 256 + threadIdx.x;   // over B*C*L
    int l  = t & (LEN - 1);
    int bc = t >> 12;
    int c  = bc & (CH - 1);
    int b  = bc >> 6;
    int k  = (int)idx_f[b * LEN + l];
    out[t] = cbk[(size_t)k * CH + c];
}

// ---------------------------------------------------------------------------
// Kernel 4: final loss reduction over NPART per-block partials.
// ---------------------------------------------------------------------------
__global__ __launch_bounds__(256) void vq_loss(const double* __restrict__ partial,
                                               float*        __restrict__ losses) {
    __shared__ double sred[256];
    double v = 0.0;
#pragma unroll
    for (int i = 0; i < NPART / 256; ++i) v += partial[threadIdx.x + 256 * i];
    sred[threadIdx.x] = v;
    __syncthreads();
    for (int s = 128; s > 0; s >>= 1) {
        if (threadIdx.x < s) sred[threadIdx.x] += sred[threadIdx.x + s];
        __syncthreads();
    }
    if (threadIdx.x == 0) {
        float loss = (float)(sred[0] / (double)((size_t)NPTS * CH));
        losses[0] = loss;   // codebook_loss
        losses[1] = loss;   // commitment_loss (same value)
    }
}

// ---------------------------------------------------------------------------
extern "C" void kernel_launch(void* const* d_in, const int* in_sizes, int n_in,
                              void* d_out, int out_size, void* d_ws, size_t ws_size,
                              hipStream_t stream) {
    const float* x  = (const float*)d_in[0];   // (B, C, L)
    const float* cb = (const float*)d_in[1];   // (K, C)
    float* out = (float*)d_out;

    // d_out: [quant_out (B*C*L)] [codebook_loss] [commitment_loss] [indices (B*L)]
    float* quant_out = out;
    float* losses    = out + (size_t)BATCH * CH * LEN;
    float* idx_out   = losses + 2;

    // ws: [0,4KB) partials(512 dbl); [4KB,8KB) w2tab; [16KB,~400KB) cbf splits
    double* partial = (double*)d_ws;
    float*  w2tab   = (float*)((char*)d_ws + 4096);
    short*  cbf     = (short*)((char*)d_ws + 16384);

    vq_prep<<<NCODE / 256, 256, 0, stream>>>(cb, cbf, w2tab);
    vq_argmin<<<NPTS / 128, 512, 0, stream>>>(x, cbf, w2tab, idx_out, partial);
    vq_gather<<<(BATCH * CH * LEN) / 256, 256, 0, stream>>>(cb, idx_out, quant_out);
    vq_loss<<<1, 256, 0, stream>>>(partial, losses);
}

// Round 17
// 76.501 us; speedup vs baseline: 31.6023x; 1.1356x over previous
//
#include <hip/hip_runtime.h>

#define BATCH 16
#define CH    64
#define LEN   4096
#define NCODE 1024
#define NPTS  (BATCH * LEN)   // 65536
#define NPART 512             // argmin blocks

typedef float float2v __attribute__((ext_vector_type(2)));
typedef float float4v __attribute__((ext_vector_type(4)));
typedef short short8  __attribute__((ext_vector_type(8)));
typedef float f32x16  __attribute__((ext_vector_type(16)));
typedef unsigned int uint32;

// RNE float->bf16 (bit ops: no dependence on __hip_bfloat16 ABI)
__device__ __forceinline__ unsigned short f2bf(float f) {
    uint32 u = __builtin_bit_cast(uint32, f);
    u += 0x7fffu + ((u >> 16) & 1u);
    return (unsigned short)(u >> 16);
}
__device__ __forceinline__ float bf2f(unsigned short h) {
    uint32 u = ((uint32)h) << 16;
    return __builtin_bit_cast(float, u);
}

// ---------------------------------------------------------------------------
// Kernel 1 (prep): split codebook into bf16x3 MFMA A-fragments + w2 table.
// A-frag layout (32x32x16 bf16): lane l holds A[row=l&31][k=16s+8*(l>>5)+i],
//   cbf[(T*12 + s*3 + sigma)*512 + lane*8 + i]   (shorts)
// w2tab[(T*2 + hi)*16 + r] = w2[T*32 + (r&3)+8*(r>>2)+4*hi]  (D-layout order)
// (identical to the r14-r16 passing version)
// ---------------------------------------------------------------------------
__global__ __launch_bounds__(256) void vq_prep(const float* __restrict__ cb,
                                               short* __restrict__ cbf,
                                               float* __restrict__ w2tab) {
    int k = blockIdx.x * 256 + threadIdx.x;    // 4 blocks x 256 = 1024 codes
    if (k >= NCODE) return;
    const int T = k >> 5, row = k & 31;
    float s2 = 0.f;
    for (int c = 0; c < CH; ++c) {
        float xv = cb[(size_t)k * CH + c];
        s2 = fmaf(xv, xv, s2);
        unsigned short h1 = f2bf(xv); float f1 = bf2f(h1);
        float r1 = xv - f1;                     // exact residual
        unsigned short h2 = f2bf(r1); float f2 = bf2f(h2);
        float r2 = r1 - f2;                     // exact residual
        unsigned short h3 = f2bf(r2);
        int s = c >> 4, kk = c & 15, g = kk >> 3, i = kk & 7;
        int lane = g * 32 + row;
        size_t base = ((size_t)T * 12 + s * 3) * 512 + lane * 8 + i;
        cbf[base]        = (short)h1;
        cbf[base + 512]  = (short)h2;
        cbf[base + 1024] = (short)h3;
    }
    int hi = (row >> 2) & 1, r = (row & 3) + 4 * (row >> 3);
    w2tab[((size_t)T * 2 + hi) * 16 + r] = s2;
}

// per-tile epilogue: cost = w2 - 2*dot, running argmin (rows ascend in k).
// w2s is the LDS copy (uniform address per lane -> broadcast ds_read).
__device__ __forceinline__ void epi(const f32x16& acc, int Tg, int g,
                                    float& bestc, int& bestk,
                                    const float* w2s) {
    const float4v* wt = (const float4v*)(w2s + ((size_t)Tg * 2 + g) * 16);
    float4v w0 = wt[0], w1 = wt[1], w2v = wt[2], w3 = wt[3];
    float wr[16] = {w0.x, w0.y, w0.z, w0.w, w1.x, w1.y, w1.z, w1.w,
                    w2v.x, w2v.y, w2v.z, w2v.w, w3.x, w3.y, w3.z, w3.w};
    int kbase = Tg * 32 + 4 * g;
#pragma unroll
    for (int r = 0; r < 16; ++r) {
        float cost = fmaf(-2.0f, acc[r], wr[r]);
        int kg = kbase + (r & 3) + 8 * (r >> 2);   // ascending in r
        if (cost < bestc) { bestc = cost; bestk = kg; }   // strict <
    }
}

// ---------------------------------------------------------------------------
// Kernel 2: MFMA argmin + fused gather.
// Direct-global codebook frags (L2-resident 384KB; no LDS staging/barriers —
// r16). NEW vs r16:
//  (a) explicit TWO-tile interleave (accA/accB): r16's single dependent MFMA
//      chain ran at latency not throughput (MfmaUtil 35% = bare work floor,
//      VGPR=64 showed unroll-2 was ignored). Two chains = 2x MFMA ILP.
//  (b) w2 table in LDS: epilogue off the vmcnt path (broadcast ds_read).
//  (c) gather fused in tail: block writes its 128 points' quant_out slice
//      coalesced (kills a dispatch + idx round-trip).
// 512 thr = 8 waves = 4 pt-subtiles x 2 code-halves; wave sweeps 8 tile-pairs.
// waves_per_eu(4,4): 128-VGPR budget (est ~124 live), 4 waves/SIMD.
// ---------------------------------------------------------------------------
__global__ void __launch_bounds__(512)
__attribute__((amdgpu_waves_per_eu(4, 4)))
vq_argmin(const float*  __restrict__ x,
          const float*  __restrict__ cb,
          const short*  __restrict__ cbf,
          const float*  __restrict__ w2tab,
          float*        __restrict__ quant,
          float*        __restrict__ idx_out,
          double*       __restrict__ partial) {
    __shared__ __attribute__((aligned(16))) float xs[CH * 128];   // 32KB
    __shared__ __attribute__((aligned(16))) float w2s[NCODE];     // 4KB
    __shared__ float  smc[8][32];
    __shared__ int    smk[8][32];
    __shared__ int    fidx[128];
    __shared__ double sds[128];

    const int t   = threadIdx.x;
    const int l   = t & 63;
    const int w   = __builtin_amdgcn_readfirstlane(t >> 6);  // 0..7
    const int h2  = w >> 2;                 // code half
    const int ptl = (w & 3) * 32 + (l & 31);
    const int g   = l >> 5;                 // k-half group
    const int p0  = blockIdx.x * 128;
    const int b   = p0 >> 12;
    const int l0  = p0 & (LEN - 1);

    // ---- stage x tile (coalesced float4) + w2 table into LDS
#pragma unroll
    for (int it = 0; it < 4; ++it) {
        int fi = it * 512 + t, c = fi >> 5, p4 = fi & 31;
        *(float4v*)&xs[c * 128 + 4 * p4] =
            *(const float4v*)&x[((size_t)b * CH + c) * LEN + l0 + 4 * p4];
    }
    w2s[t]       = w2tab[t];
    w2s[t + 512] = w2tab[t + 512];
    __syncthreads();

    // ---- build B-frags (x splits) ONCE + x2 partial over my 32 channels
    short8 B1[4], B2[4], B3[4];
    float x2p = 0.f;
#pragma unroll
    for (int s = 0; s < 4; ++s) {
#pragma unroll
        for (int i = 0; i < 8; ++i) {
            int c = s * 16 + g * 8 + i;     // same k-mapping as A frags
            float xv = xs[c * 128 + ptl];
            x2p = fmaf(xv, xv, x2p);
            unsigned short h1v = f2bf(xv); float f1 = bf2f(h1v);
            float r1 = xv - f1;
            unsigned short h2v = f2bf(r1); float f2 = bf2f(h2v);
            float r2 = r1 - f2;
            unsigned short h3v = f2bf(r2);
            B1[s][i] = (short)h1v; B2[s][i] = (short)h2v; B3[s][i] = (short)h3v;
        }
    }
    const float x2 = x2p + __shfl_xor(x2p, 32, 64);   // lane pairs share point

    float bestc = 3.4e38f;
    int   bestk = 0;

    // ---- sweep this wave's 16 code tiles as 8 pairs (two indep acc chains)
    for (int tt = 0; tt < 8; ++tt) {
        const int tlA = h2 * 16 + 2 * tt;
        const short* fpA = cbf + ((size_t)tlA * 12) * 512 + l * 8;
        const short* fpB = fpA + 12 * 512;
        f32x16 accA = {0.f,0.f,0.f,0.f,0.f,0.f,0.f,0.f,
                       0.f,0.f,0.f,0.f,0.f,0.f,0.f,0.f};
        f32x16 accB = accA;
#pragma unroll
        for (int s = 0; s < 4; ++s) {
            const short* fa = fpA + (s * 3) * 512;
            const short* fb = fpB + (s * 3) * 512;
            short8 A1a = *(const short8*)(fa);
            short8 A2a = *(const short8*)(fa + 512);
            short8 A3a = *(const short8*)(fa + 1024);
            short8 A1b = *(const short8*)(fb);
            short8 A2b = *(const short8*)(fb + 512);
            short8 A3b = *(const short8*)(fb + 1024);
            // 6 split terms x 2 tiles, chains interleaved
            accA = __builtin_amdgcn_mfma_f32_32x32x16_bf16(A1a, B1[s], accA, 0, 0, 0);
            accB = __builtin_amdgcn_mfma_f32_32x32x16_bf16(A1b, B1[s], accB, 0, 0, 0);
            accA = __builtin_amdgcn_mfma_f32_32x32x16_bf16(A1a, B2[s], accA, 0, 0, 0);
            accB = __builtin_amdgcn_mfma_f32_32x32x16_bf16(A1b, B2[s], accB, 0, 0, 0);
            accA = __builtin_amdgcn_mfma_f32_32x32x16_bf16(A2a, B1[s], accA, 0, 0, 0);
            accB = __builtin_amdgcn_mfma_f32_32x32x16_bf16(A2b, B1[s], accB, 0, 0, 0);
            accA = __builtin_amdgcn_mfma_f32_32x32x16_bf16(A1a, B3[s], accA, 0, 0, 0);
            accB = __builtin_amdgcn_mfma_f32_32x32x16_bf16(A1b, B3[s], accB, 0, 0, 0);
            accA = __builtin_amdgcn_mfma_f32_32x32x16_bf16(A3a, B1[s], accA, 0, 0, 0);
            accB = __builtin_amdgcn_mfma_f32_32x32x16_bf16(A3b, B1[s], accB, 0, 0, 0);
            accA = __builtin_amdgcn_mfma_f32_32x32x16_bf16(A2a, B2[s], accA, 0, 0, 0);
            accB = __builtin_amdgcn_mfma_f32_32x32x16_bf16(A2b, B2[s], accB, 0, 0, 0);
        }
        epi(accA, tlA,     g, bestc, bestk, w2s);
        epi(accB, tlA + 1, g, bestc, bestk, w2s);
    }

    // ---- merge g-halves within wave (explicit smaller-k tie-break)
    {
        float ob = __shfl_xor(bestc, 32, 64);
        int   ok = __shfl_xor(bestk, 32, 64);
        if (ob < bestc || (ob == bestc && ok < bestk)) { bestc = ob; bestk = ok; }
    }
    // ---- merge the two code-half waves per point via LDS
    if (l < 32) { smc[w][l] = bestc; smk[w][l] = bestk; }
    __syncthreads();
    if (w < 4 && l < 32) {
        float ob = smc[w + 4][l];
        int   ok = smk[w + 4][l];
        if (ob < bestc || (ob == bestc && ok < bestk)) { bestc = ob; bestk = ok; }
        idx_out[p0 + w * 32 + l] = (float)bestk;
        fidx[w * 32 + l] = bestk;
        sds[w * 32 + l] = (double)x2 + (double)bestc;   // min d2 = x2 + (w2-2dot)
    }
    __syncthreads();

    // ---- fused gather: quant[b][c][l0+pt] = cb[fidx[pt]][c]
    {
        const int pt = t & 127;
        const int cq = t >> 7;           // 4 channel quarters x 16 ch
        const int k  = fidx[pt];
        const float4v* src = (const float4v*)(cb + (size_t)k * CH + cq * 16);
        float4v v0 = src[0], v1 = src[1], v2 = src[2], v3 = src[3];
        float vr[16] = {v0.x, v0.y, v0.z, v0.w, v1.x, v1.y, v1.z, v1.w,
                        v2.x, v2.y, v2.z, v2.w, v3.x, v3.y, v3.z, v3.w};
#pragma unroll
        for (int j = 0; j < 16; ++j) {
            int c = cq * 16 + j;
            quant[((size_t)b * CH + c) * LEN + l0 + pt] = vr[j];  // coalesced in pt
        }
    }

    if (t == 0) {
        double s = 0.0;
        for (int i = 0; i < 128; ++i) s += sds[i];
        partial[blockIdx.x] = s;
    }
}

// ---------------------------------------------------------------------------
// Kernel 3: final loss reduction over NPART per-block partials.
// ---------------------------------------------------------------------------
__global__ __launch_bounds__(256) void vq_loss(const double* __restrict__ partial,
                                               float*        __restrict__ losses) {
    __shared__ double sred[256];
    double v = 0.0;
#pragma unroll
    for (int i = 0; i < NPART / 256; ++i) v += partial[threadIdx.x + 256 * i];
    sred[threadIdx.x] = v;
    __syncthreads();
    for (int s = 128; s > 0; s >>= 1) {
        if (threadIdx.x < s) sred[threadIdx.x] += sred[threadIdx.x + s];
        __syncthreads();
    }
    if (threadIdx.x == 0) {
        float loss = (float)(sred[0] / (double)((size_t)NPTS * CH));
        losses[0] = loss;   // codebook_loss
        losses[1] = loss;   // commitment_loss (same value)
    }
}

// ---------------------------------------------------------------------------
extern "C" void kernel_launch(void* const* d_in, const int* in_sizes, int n_in,
                              void* d_out, int out_size, void* d_ws, size_t ws_size,
                              hipStream_t stream) {
    const float* x  = (const float*)d_in[0];   // (B, C, L)
    const float* cb = (const float*)d_in[1];   // (K, C)
    float* out = (float*)d_out;

    // d_out: [quant_out (B*C*L)] [codebook_loss] [commitment_loss] [indices (B*L)]
    float* quant_out = out;
    float* losses    = out + (size_t)BATCH * CH * LEN;
    float* idx_out   = losses + 2;

    // ws: [0,4KB) partials(512 dbl); [4KB,8KB) w2tab; [16KB,~400KB) cbf splits
    double* partial = (double*)d_ws;
    float*  w2tab   = (float*)((char*)d_ws + 4096);
    short*  cbf     = (short*)((char*)d_ws + 16384);

    vq_prep<<<NCODE / 256, 256, 0, stream>>>(cb, cbf, w2tab);
    vq_argmin<<<NPTS / 128, 512, 0, stream>>>(x, cb, cbf, w2tab,
                                              quant_out, idx_out, partial);
    vq_loss<<<1, 256, 0, stream>>>(partial, losses);
}

// Round 18
// 72.409 us; speedup vs baseline: 33.3882x; 1.0565x over previous
//
#include <hip/hip_runtime.h>

#define BATCH 16
#define CH    64
#define LEN   4096
#define NCODE 1024
#define NPTS  (BATCH * LEN)   // 65536
#define NPART 512             // argmin blocks
#define UNITB 24576           // staging unit: 2 tiles (one per code-half) = 24KB

typedef float float2v __attribute__((ext_vector_type(2)));
typedef float float4v __attribute__((ext_vector_type(4)));
typedef short short8  __attribute__((ext_vector_type(8)));
typedef float f32x16  __attribute__((ext_vector_type(16)));
typedef unsigned int uint32;

// RNE float->bf16 (bit ops: no dependence on __hip_bfloat16 ABI)
__device__ __forceinline__ unsigned short f2bf(float f) {
    uint32 u = __builtin_bit_cast(uint32, f);
    u += 0x7fffu + ((u >> 16) & 1u);
    return (unsigned short)(u >> 16);
}
__device__ __forceinline__ float bf2f(unsigned short h) {
    uint32 u = ((uint32)h) << 16;
    return __builtin_bit_cast(float, u);
}

// ---------------------------------------------------------------------------
// Kernel 1 (prep): split codebook into bf16x3 MFMA A-fragments + w2 table.
// NEW layout: step-unit contiguous. Original tile T (32 codes) maps to
//   unit u = T<16 ? T : T-16,  pos p = T<16 ? 0 : 1
//   cbf2[ ((u*2+p)*12 + s*3+sigma)*512 + lane*8 + i ]
// -> step t stages one contiguous 24KB unit holding both code-halves' tiles.
// w2tab unchanged (indexed by ORIGINAL tile T, D-layout order).
// ---------------------------------------------------------------------------
__global__ __launch_bounds__(256) void vq_prep(const float* __restrict__ cb,
                                               short* __restrict__ cbf2,
                                               float* __restrict__ w2tab) {
    int k = blockIdx.x * 256 + threadIdx.x;    // 4 blocks x 256 = 1024 codes
    if (k >= NCODE) return;
    const int T = k >> 5, row = k & 31;
    const int Tp = (T < 16) ? (T * 2) : ((T - 16) * 2 + 1);   // unit-contiguous
    float s2 = 0.f;
    for (int c = 0; c < CH; ++c) {
        float xv = cb[(size_t)k * CH + c];
        s2 = fmaf(xv, xv, s2);
        unsigned short h1 = f2bf(xv); float f1 = bf2f(h1);
        float r1 = xv - f1;                     // exact residual
        unsigned short h2 = f2bf(r1); float f2 = bf2f(h2);
        float r2 = r1 - f2;                     // exact residual
        unsigned short h3 = f2bf(r2);
        int s = c >> 4, kk = c & 15, g = kk >> 3, i = kk & 7;
        int lane = g * 32 + row;
        size_t base = ((size_t)Tp * 12 + s * 3) * 512 + lane * 8 + i;
        cbf2[base]        = (short)h1;
        cbf2[base + 512]  = (short)h2;
        cbf2[base + 1024] = (short)h3;
    }
    int hi = (row >> 2) & 1, r = (row & 3) + 4 * (row >> 3);
    w2tab[((size_t)T * 2 + hi) * 16 + r] = s2;
}

// per-tile epilogue: cost = w2 - 2*dot, running argmin (rows ascend in k).
__device__ __forceinline__ void epi(const f32x16& acc, int Tg, int g,
                                    float& bestc, int& bestk,
                                    const float* w2s) {
    const float4v* wt = (const float4v*)(w2s + ((size_t)Tg * 2 + g) * 16);
    float4v w0 = wt[0], w1 = wt[1], w2v = wt[2], w3 = wt[3];
    float wr[16] = {w0.x, w0.y, w0.z, w0.w, w1.x, w1.y, w1.z, w1.w,
                    w2v.x, w2v.y, w2v.z, w2v.w, w3.x, w3.y, w3.z, w3.w};
    int kbase = Tg * 32 + 4 * g;
#pragma unroll
    for (int r = 0; r < 16; ++r) {
        float cost = fmaf(-2.0f, acc[r], wr[r]);
        int kg = kbase + (r & 3) + 8 * (r >> 2);   // ascending in r
        if (cost < bestc) { bestc = cost; bestk = kg; }   // strict <
    }
}

// ---------------------------------------------------------------------------
// Kernel 2: MFMA argmin + fused gather, LDS-ring pipelined codebook.
// r17 counters: MfmaUtil 34.6% x 62us = 21.4us busy = the work floor; pipe
// idle 65% on per-tile cold L2 waits (~250cy) because prefetching A-frags in
// registers needs +96 VGPR (impossible at 128 budget). Fix: 3-slot LDS ring;
// per step: issue unit(t+2) global->reg loads (12 VGPR, land under MFMAs),
// compute tile t from ring (ds_read ~12cy), ds_write unit(t+1), ONE raw
// s_barrier (NOT __syncthreads: its vmcnt(0) drain would kill the in-flight
// prefetch - the documented m97-ceiling mechanism). Slot reuse is 3 barriers
// deep. Compiler fences pin ds ops to barrier. Math/order identical to r17.
// ---------------------------------------------------------------------------
__global__ void __launch_bounds__(512)
__attribute__((amdgpu_waves_per_eu(4, 4)))
vq_argmin(const float*  __restrict__ x,
          const float*  __restrict__ cb,
          const short*  __restrict__ cbf2,
          const float*  __restrict__ w2tab,
          float*        __restrict__ quant,
          float*        __restrict__ idx_out,
          double*       __restrict__ partial) {
    __shared__ __attribute__((aligned(16))) char  ring[3 * UNITB];  // 72KB
    __shared__ __attribute__((aligned(16))) float w2s[NCODE];       // 4KB
    __shared__ float  smc[8][32];
    __shared__ int    smk[8][32];
    __shared__ int    fidx[128];
    __shared__ double sds[128];

    const int t   = threadIdx.x;
    const int l   = t & 63;
    const int w   = __builtin_amdgcn_readfirstlane(t >> 6);  // 0..7
    const int h2  = w >> 2;                 // code half
    const int ptl = (w & 3) * 32 + (l & 31);
    const int g   = l >> 5;                 // k-half group
    const int p0  = blockIdx.x * 128;
    const int b   = p0 >> 12;
    const int l0  = p0 & (LEN - 1);

    float* xs = (float*)ring;               // x tile overlays ring[0:32KB)

    // ---- stage x tile (coalesced float4) + w2 table into LDS
#pragma unroll
    for (int it = 0; it < 4; ++it) {
        int fi = it * 512 + t, c = fi >> 5, p4 = fi & 31;
        *(float4v*)&xs[c * 128 + 4 * p4] =
            *(const float4v*)&x[((size_t)b * CH + c) * LEN + l0 + 4 * p4];
    }
    w2s[t]       = w2tab[t];
    w2s[t + 512] = w2tab[t + 512];
    __syncthreads();

    // ---- build B-frags (x splits) ONCE + x2 partial over my 32 channels
    short8 B1[4], B2[4], B3[4];
    float x2p = 0.f;
#pragma unroll
    for (int s = 0; s < 4; ++s) {
#pragma unroll
        for (int i = 0; i < 8; ++i) {
            int c = s * 16 + g * 8 + i;     // same k-mapping as A frags
            float xv = xs[c * 128 + ptl];
            x2p = fmaf(xv, xv, x2p);
            unsigned short h1v = f2bf(xv); float f1 = bf2f(h1v);
            float r1 = xv - f1;
            unsigned short h2v = f2bf(r1); float f2 = bf2f(h2v);
            float r2 = r1 - f2;
            unsigned short h3v = f2bf(r2);
            B1[s][i] = (short)h1v; B2[s][i] = (short)h2v; B3[s][i] = (short)h3v;
        }
    }
    const float x2 = x2p + __shfl_xor(x2p, 32, 64);   // lane pairs share point
    __syncthreads();                        // xs dead; ring reuse begins

    const float4v* gsrc = (const float4v*)cbf2;   // 1536 float4 per unit

    // ---- prologue: unit0 -> slot0; unit1 loads in flight
    float4v sA0, sA1, sA2, sB0, sB1, sB2;
    sA0 = gsrc[t]; sA1 = gsrc[512 + t]; sA2 = gsrc[1024 + t];
    {
        float4v* d = (float4v*)ring;
        d[t] = sA0; d[512 + t] = sA1; d[1024 + t] = sA2;
    }
    sA0 = gsrc[1536 + t]; sA1 = gsrc[2048 + t]; sA2 = gsrc[2560 + t];  // unit1
    asm volatile("" ::: "memory");
    __builtin_amdgcn_s_barrier();           // slot0 visible to all waves
    asm volatile("" ::: "memory");

    float bestc = 3.4e38f;
    int   bestk = 0;

    // one pipeline step: compute tile tt from ring, prefetch unit tt+2 into
    // (nx*), write unit tt+1 (held in cu*) to its slot, raw barrier.
    auto STEP = [&](int tt, float4v& cu0, float4v& cu1, float4v& cu2,
                    float4v& nx0, float4v& nx1, float4v& nx2) {
        if (tt + 2 < 16) {
            const float4v* gs = gsrc + (size_t)(tt + 2) * 1536;
            nx0 = gs[t]; nx1 = gs[512 + t]; nx2 = gs[1024 + t];
        }
        // ---- compute tile tt (true tile Tg = h2*16+tt) from slot tt%3
        const short* bp = (const short*)&ring[(tt % 3) * UNITB] + h2 * 6144;
        f32x16 acc = {0.f,0.f,0.f,0.f,0.f,0.f,0.f,0.f,
                      0.f,0.f,0.f,0.f,0.f,0.f,0.f,0.f};
#pragma unroll
        for (int s = 0; s < 4; ++s) {
            const short* fb = bp + (s * 3) * 512 + l * 8;
            short8 A1 = *(const short8*)(fb);
            short8 A2 = *(const short8*)(fb + 512);
            short8 A3 = *(const short8*)(fb + 1024);
            acc = __builtin_amdgcn_mfma_f32_32x32x16_bf16(A1, B1[s], acc, 0, 0, 0);
            acc = __builtin_amdgcn_mfma_f32_32x32x16_bf16(A1, B2[s], acc, 0, 0, 0);
            acc = __builtin_amdgcn_mfma_f32_32x32x16_bf16(A2, B1[s], acc, 0, 0, 0);
            acc = __builtin_amdgcn_mfma_f32_32x32x16_bf16(A1, B3[s], acc, 0, 0, 0);
            acc = __builtin_amdgcn_mfma_f32_32x32x16_bf16(A3, B1[s], acc, 0, 0, 0);
            acc = __builtin_amdgcn_mfma_f32_32x32x16_bf16(A2, B2[s], acc, 0, 0, 0);
        }
        epi(acc, h2 * 16 + tt, g, bestc, bestk, w2s);
        // ---- write unit tt+1 (loaded last step into cu*) to slot (tt+1)%3
        if (tt + 1 < 16) {
            float4v* d = (float4v*)&ring[((tt + 1) % 3) * UNITB];
            d[t] = cu0; d[512 + t] = cu1; d[1024 + t] = cu2;
        }
        asm volatile("" ::: "memory");
        __builtin_amdgcn_s_barrier();       // raw: vmcnt prefetch stays in flight
        asm volatile("" ::: "memory");
    };

    for (int tp = 0; tp < 8; ++tp) {
        STEP(2 * tp,     sA0, sA1, sA2, sB0, sB1, sB2);
        STEP(2 * tp + 1, sB0, sB1, sB2, sA0, sA1, sA2);
    }

    // ---- merge g-halves within wave (explicit smaller-k tie-break)
    {
        float ob = __shfl_xor(bestc, 32, 64);
        int   ok = __shfl_xor(bestk, 32, 64);
        if (ob < bestc || (ob == bestc && ok < bestk)) { bestc = ob; bestk = ok; }
    }
    // ---- merge the two code-half waves per point via LDS
    if (l < 32) { smc[w][l] = bestc; smk[w][l] = bestk; }
    __syncthreads();
    if (w < 4 && l < 32) {
        float ob = smc[w + 4][l];
        int   ok = smk[w + 4][l];
        if (ob < bestc || (ob == bestc && ok < bestk)) { bestc = ob; bestk = ok; }
        idx_out[p0 + w * 32 + l] = (float)bestk;
        fidx[w * 32 + l] = bestk;
        sds[w * 32 + l] = (double)x2 + (double)bestc;   // min d2 = x2 + (w2-2dot)
    }
    __syncthreads();

    // ---- fused gather: quant[b][c][l0+pt] = cb[fidx[pt]][c]
    {
        const int pt = t & 127;
        const int cq = t >> 7;           // 4 channel quarters x 16 ch
        const int k  = fidx[pt];
        const float4v* src = (const float4v*)(cb + (size_t)k * CH + cq * 16);
        float4v v0 = src[0], v1 = src[1], v2 = src[2], v3 = src[3];
        float vr[16] = {v0.x, v0.y, v0.z, v0.w, v1.x, v1.y, v1.z, v1.w,
                        v2.x, v2.y, v2.z, v2.w, v3.x, v3.y, v3.z, v3.w};
#pragma unroll
        for (int j = 0; j < 16; ++j) {
            int c = cq * 16 + j;
            quant[((size_t)b * CH + c) * LEN + l0 + pt] = vr[j];  // coalesced in pt
        }
    }

    if (t == 0) {
        double s = 0.0;
        for (int i = 0; i < 128; ++i) s += sds[i];
        partial[blockIdx.x] = s;
    }
}

// ---------------------------------------------------------------------------
// Kernel 3: final loss reduction over NPART per-block partials.
// ---------------------------------------------------------------------------
__global__ __launch_bounds__(256) void vq_loss(const double* __restrict__ partial,
                                               float*        __restrict__ losses) {
    __shared__ double sred[256];
    double v = 0.0;
#pragma unroll
    for (int i = 0; i < NPART / 256; ++i) v += partial[threadIdx.x + 256 * i];
    sred[threadIdx.x] = v;
    __syncthreads();
    for (int s = 128; s > 0; s >>= 1) {
        if (threadIdx.x < s) sred[threadIdx.x] += sred[threadIdx.x + s];
        __syncthreads();
    }
    if (threadIdx.x == 0) {
        float loss = (float)(sred[0] / (double)((size_t)NPTS * CH));
        losses[0] = loss;   // codebook_loss
        losses[1] = loss;   // commitment_loss (same value)
    }
}

// ---------------------------------------------------------------------------
extern "C" void kernel_launch(void* const* d_in, const int* in_sizes, int n_in,
                              void* d_out, int out_size, void* d_ws, size_t ws_size,
                              hipStream_t stream) {
    const float* x  = (const float*)d_in[0];   // (B, C, L)
    const float* cb = (const float*)d_in[1];   // (K, C)
    float* out = (float*)d_out;

    // d_out: [quant_out (B*C*L)] [codebook_loss] [commitment_loss] [indices (B*L)]
    float* quant_out = out;
    float* losses    = out + (size_t)BATCH * CH * LEN;
    float* idx_out   = losses + 2;

    // ws: [0,4KB) partials(512 dbl); [4KB,8KB) w2tab; [16KB,~400KB) cbf2 splits
    double* partial = (double*)d_ws;
    float*  w2tab   = (float*)((char*)d_ws + 4096);
    short*  cbf2    = (short*)((char*)d_ws + 16384);

    vq_prep<<<NCODE / 256, 256, 0, stream>>>(cb, cbf2, w2tab);
    vq_argmin<<<NPTS / 128, 512, 0, stream>>>(x, cb, cbf2, w2tab,
                                              quant_out, idx_out, partial);
    vq_loss<<<1, 256, 0, stream>>>(partial, losses);
}

// Round 19
// 70.867 us; speedup vs baseline: 34.1150x; 1.0218x over previous
//
#include <hip/hip_runtime.h>

#define BATCH 16
#define CH    64
#define LEN   4096
#define NCODE 1024
#define NPTS  (BATCH * LEN)   // 65536
#define NPART 512             // argmin blocks
#define UNITB 24576           // staging unit: 2 tiles (one per code-half) = 24KB

typedef float float2v __attribute__((ext_vector_type(2)));
typedef float float4v __attribute__((ext_vector_type(4)));
typedef short short8  __attribute__((ext_vector_type(8)));
typedef float f32x16  __attribute__((ext_vector_type(16)));
typedef unsigned int uint32;

// RNE float->bf16 (bit ops: no dependence on __hip_bfloat16 ABI)
__device__ __forceinline__ unsigned short f2bf(float f) {
    uint32 u = __builtin_bit_cast(uint32, f);
    u += 0x7fffu + ((u >> 16) & 1u);
    return (unsigned short)(u >> 16);
}
__device__ __forceinline__ float bf2f(unsigned short h) {
    uint32 u = ((uint32)h) << 16;
    return __builtin_bit_cast(float, u);
}

// ---------------------------------------------------------------------------
// Kernel 1 (prep): split codebook into bf16x3 MFMA A-fragments + w2 table.
// Step-unit contiguous layout (r18): tile T -> unit pos Tp = T<16 ? 2T : 2(T-16)+1
//   cbf2[(Tp*12 + s*3 + sigma)*512 + lane*8 + i]
// NEW: 16 blocks x 256 thr, coalesced LDS-tiled staging (r18's 4-block version
// did 64 strided uncoalesced loads/thread = ~7us of latency on 16 waves).
// 4 threads per code (one 16-ch quarter each, = k-slice s), LDS s2 combine.
// ---------------------------------------------------------------------------
__global__ __launch_bounds__(256) void vq_prep(const float* __restrict__ cb,
                                               short* __restrict__ cbf2,
                                               float* __restrict__ w2tab) {
    __shared__ float tile[64][65];
    __shared__ float s2p[4][64];
    const int k0 = blockIdx.x * 64;
    const int t  = threadIdx.x;
    // stage 64 codes x 64 ch, coalesced float4
#pragma unroll
    for (int it = 0; it < 4; ++it) {
        int idx = it * 256 + t, row = idx >> 4, q = idx & 15;
        *(float4v*)&tile[row][q * 4] =
            *(const float4v*)&cb[(size_t)(k0 + row) * CH + q * 4];
    }
    __syncthreads();

    const int j  = t & 63;         // code within block
    const int cq = t >> 6;         // channel quarter == k-slice s
    const int k  = k0 + j, T = k >> 5, row = k & 31;
    const int Tp = (T < 16) ? (T * 2) : ((T - 16) * 2 + 1);
    float s2 = 0.f;
#pragma unroll
    for (int cc = 0; cc < 16; ++cc) {
        float xv = tile[j][cq * 16 + cc];
        s2 = fmaf(xv, xv, s2);
        unsigned short h1 = f2bf(xv); float f1 = bf2f(h1);
        float r1 = xv - f1;                     // exact residual
        unsigned short h2 = f2bf(r1); float f2 = bf2f(h2);
        float r2 = r1 - f2;                     // exact residual
        unsigned short h3 = f2bf(r2);
        int g = cc >> 3, i = cc & 7;
        int lane = g * 32 + row;
        size_t base = ((size_t)Tp * 12 + cq * 3) * 512 + lane * 8 + i;
        cbf2[base]        = (short)h1;
        cbf2[base + 512]  = (short)h2;
        cbf2[base + 1024] = (short)h3;
    }
    s2p[cq][j] = s2;
    __syncthreads();
    if (t < 64) {
        float s2t = ((s2p[0][t] + s2p[1][t]) + (s2p[2][t] + s2p[3][t]));
        int kk = k0 + t, TT = kk >> 5, rr = kk & 31;
        int hi = (rr >> 2) & 1, r = (rr & 3) + 4 * (rr >> 3);
        w2tab[((size_t)TT * 2 + hi) * 16 + r] = s2t;
    }
}

// per-tile epilogue: cost = w2 - 2*dot, running argmin (rows ascend in k).
__device__ __forceinline__ void epi(const f32x16& acc, int Tg, int g,
                                    float& bestc, int& bestk,
                                    const float* w2s) {
    const float4v* wt = (const float4v*)(w2s + ((size_t)Tg * 2 + g) * 16);
    float4v w0 = wt[0], w1 = wt[1], w2v = wt[2], w3 = wt[3];
    float wr[16] = {w0.x, w0.y, w0.z, w0.w, w1.x, w1.y, w1.z, w1.w,
                    w2v.x, w2v.y, w2v.z, w2v.w, w3.x, w3.y, w3.z, w3.w};
    int kbase = Tg * 32 + 4 * g;
#pragma unroll
    for (int r = 0; r < 16; ++r) {
        float cost = fmaf(-2.0f, acc[r], wr[r]);
        int kg = kbase + (r & 3) + 8 * (r >> 2);   // ascending in r
        if (cost < bestc) { bestc = cost; bestk = kg; }   // strict <
    }
}

// ---------------------------------------------------------------------------
// Kernel 2: MFMA argmin + fused gather, 2-slot LDS-ring pipelined codebook.
// r18 counters: LDS 81KB -> 1 block/CU -> 2 waves/SIMD; single dependent
// 24-MFMA chain at dep-latency -> MfmaUtil 40%. Fixes:
//  (a) ring 3->2 slots (48KB; same 1-barrier write->read discipline) ->
//      LDS ~55.5KB -> 2 blocks/CU -> 4 waves/SIMD.
//  (b) dual acc chains per tile (acc1: {A1,A2,A3}xB1; acc2: A1x{B2,B3}+A2xB2;
//      elementwise sum before epi) -> 2 indep chains/wave, 8/SIMD.
//  (c) explicit s_waitcnt lgkmcnt(0) before each raw s_barrier (cross-wave
//      ds_write visibility; r18 relied on timing).
// Raw s_barrier keeps the unit(t+2) global prefetch in flight (no vmcnt
// drain - the m97-ceiling mechanism). Math/k-mapping/tie-breaks = r18.
// ---------------------------------------------------------------------------
__global__ void __launch_bounds__(512)
__attribute__((amdgpu_waves_per_eu(4, 4)))
vq_argmin(const float*  __restrict__ x,
          const float*  __restrict__ cb,
          const short*  __restrict__ cbf2,
          const float*  __restrict__ w2tab,
          float*        __restrict__ quant,
          float*        __restrict__ idx_out,
          double*       __restrict__ partial) {
    __shared__ __attribute__((aligned(16))) char  ring[2 * UNITB];  // 48KB
    __shared__ __attribute__((aligned(16))) float w2s[NCODE];       // 4KB
    __shared__ float  smc[8][32];
    __shared__ int    smk[8][32];
    __shared__ int    fidx[128];
    __shared__ double sds[128];

    const int t   = threadIdx.x;
    const int l   = t & 63;
    const int w   = __builtin_amdgcn_readfirstlane(t >> 6);  // 0..7
    const int h2  = w >> 2;                 // code half
    const int ptl = (w & 3) * 32 + (l & 31);
    const int g   = l >> 5;                 // k-half group
    const int p0  = blockIdx.x * 128;
    const int b   = p0 >> 12;
    const int l0  = p0 & (LEN - 1);

    float* xs = (float*)ring;               // x tile overlays the ring (32KB)

    // ---- stage x tile (coalesced float4) + w2 table into LDS
#pragma unroll
    for (int it = 0; it < 4; ++it) {
        int fi = it * 512 + t, c = fi >> 5, p4 = fi & 31;
        *(float4v*)&xs[c * 128 + 4 * p4] =
            *(const float4v*)&x[((size_t)b * CH + c) * LEN + l0 + 4 * p4];
    }
    w2s[t]       = w2tab[t];
    w2s[t + 512] = w2tab[t + 512];
    __syncthreads();

    // ---- build B-frags (x splits) ONCE + x2 partial over my 32 channels
    short8 B1[4], B2[4], B3[4];
    float x2p = 0.f;
#pragma unroll
    for (int s = 0; s < 4; ++s) {
#pragma unroll
        for (int i = 0; i < 8; ++i) {
            int c = s * 16 + g * 8 + i;     // same k-mapping as A frags
            float xv = xs[c * 128 + ptl];
            x2p = fmaf(xv, xv, x2p);
            unsigned short h1v = f2bf(xv); float f1 = bf2f(h1v);
            float r1 = xv - f1;
            unsigned short h2v = f2bf(r1); float f2 = bf2f(h2v);
            float r2 = r1 - f2;
            unsigned short h3v = f2bf(r2);
            B1[s][i] = (short)h1v; B2[s][i] = (short)h2v; B3[s][i] = (short)h3v;
        }
    }
    const float x2 = x2p + __shfl_xor(x2p, 32, 64);   // lane pairs share point
    __syncthreads();                        // xs dead; ring reuse begins

    const float4v* gsrc = (const float4v*)cbf2;   // 1536 float4 per unit

    // ---- prologue: unit0 -> slot0; unit1 loads in flight
    float4v sA0, sA1, sA2, sB0, sB1, sB2;
    sA0 = gsrc[t]; sA1 = gsrc[512 + t]; sA2 = gsrc[1024 + t];
    {
        float4v* d = (float4v*)ring;
        d[t] = sA0; d[512 + t] = sA1; d[1024 + t] = sA2;
    }
    sA0 = gsrc[1536 + t]; sA1 = gsrc[2048 + t]; sA2 = gsrc[2560 + t];  // unit1
    asm volatile("s_waitcnt lgkmcnt(0)" ::: "memory");
    __builtin_amdgcn_s_barrier();           // slot0 visible; unit1 vmcnt in flight
    asm volatile("" ::: "memory");

    float bestc = 3.4e38f;
    int   bestk = 0;

    // one pipeline step: prefetch unit tt+2 -> nx regs, compute tile tt from
    // slot tt&1 (dual acc chains), write unit tt+1 (cu regs) -> slot (tt+1)&1,
    // lgkm-wait + raw barrier.
    auto STEP = [&](int tt, float4v& cu0, float4v& cu1, float4v& cu2,
                    float4v& nx0, float4v& nx1, float4v& nx2) {
        if (tt + 2 < 16) {
            const float4v* gs = gsrc + (size_t)(tt + 2) * 1536;
            nx0 = gs[t]; nx1 = gs[512 + t]; nx2 = gs[1024 + t];
        }
        const short* bp = (const short*)&ring[(tt & 1) * UNITB] + h2 * 6144;
        f32x16 acc1 = {0.f,0.f,0.f,0.f,0.f,0.f,0.f,0.f,
                       0.f,0.f,0.f,0.f,0.f,0.f,0.f,0.f};
        f32x16 acc2 = acc1;
#pragma unroll
        for (int s = 0; s < 4; ++s) {
            const short* fb = bp + (s * 3) * 512 + l * 8;
            short8 A1 = *(const short8*)(fb);
            short8 A2 = *(const short8*)(fb + 512);
            short8 A3 = *(const short8*)(fb + 1024);
            // 6 split terms, two independent chains
            acc1 = __builtin_amdgcn_mfma_f32_32x32x16_bf16(A1, B1[s], acc1, 0, 0, 0);
            acc2 = __builtin_amdgcn_mfma_f32_32x32x16_bf16(A1, B2[s], acc2, 0, 0, 0);
            acc1 = __builtin_amdgcn_mfma_f32_32x32x16_bf16(A2, B1[s], acc1, 0, 0, 0);
            acc2 = __builtin_amdgcn_mfma_f32_32x32x16_bf16(A1, B3[s], acc2, 0, 0, 0);
            acc1 = __builtin_amdgcn_mfma_f32_32x32x16_bf16(A3, B1[s], acc1, 0, 0, 0);
            acc2 = __builtin_amdgcn_mfma_f32_32x32x16_bf16(A2, B2[s], acc2, 0, 0, 0);
        }
        f32x16 acc = acc1 + acc2;
        epi(acc, h2 * 16 + tt, g, bestc, bestk, w2s);
        if (tt + 1 < 16) {
            float4v* d = (float4v*)&ring[((tt + 1) & 1) * UNITB];
            d[t] = cu0; d[512 + t] = cu1; d[1024 + t] = cu2;
        }
        asm volatile("s_waitcnt lgkmcnt(0)" ::: "memory");
        __builtin_amdgcn_s_barrier();       // raw: vmcnt prefetch stays in flight
        asm volatile("" ::: "memory");
    };

    for (int tp = 0; tp < 8; ++tp) {
        STEP(2 * tp,     sA0, sA1, sA2, sB0, sB1, sB2);
        STEP(2 * tp + 1, sB0, sB1, sB2, sA0, sA1, sA2);
    }

    // ---- merge g-halves within wave (explicit smaller-k tie-break)
    {
        float ob = __shfl_xor(bestc, 32, 64);
        int   ok = __shfl_xor(bestk, 32, 64);
        if (ob < bestc || (ob == bestc && ok < bestk)) { bestc = ob; bestk = ok; }
    }
    // ---- merge the two code-half waves per point via LDS
    if (l < 32) { smc[w][l] = bestc; smk[w][l] = bestk; }
    __syncthreads();
    if (w < 4 && l < 32) {
        float ob = smc[w + 4][l];
        int   ok = smk[w + 4][l];
        if (ob < bestc || (ob == bestc && ok < bestk)) { bestc = ob; bestk = ok; }
        idx_out[p0 + w * 32 + l] = (float)bestk;
        fidx[w * 32 + l] = bestk;
        sds[w * 32 + l] = (double)x2 + (double)bestc;   // min d2 = x2 + (w2-2dot)
    }
    __syncthreads();

    // ---- fused gather: quant[b][c][l0+pt] = cb[fidx[pt]][c]
    {
        const int pt = t & 127;
        const int cq = t >> 7;           // 4 channel quarters x 16 ch
        const int k  = fidx[pt];
        const float4v* src = (const float4v*)(cb + (size_t)k * CH + cq * 16);
        float4v v0 = src[0], v1 = src[1], v2 = src[2], v3 = src[3];
        float vr[16] = {v0.x, v0.y, v0.z, v0.w, v1.x, v1.y, v1.z, v1.w,
                        v2.x, v2.y, v2.z, v2.w, v3.x, v3.y, v3.z, v3.w};
#pragma unroll
        for (int j = 0; j < 16; ++j) {
            int c = cq * 16 + j;
            quant[((size_t)b * CH + c) * LEN + l0 + pt] = vr[j];  // coalesced in pt
        }
    }

    if (t == 0) {
        double s = 0.0;
        for (int i = 0; i < 128; ++i) s += sds[i];
        partial[blockIdx.x] = s;
    }
}

// ---------------------------------------------------------------------------
// Kernel 3: final loss reduction over NPART per-block partials.
// ---------------------------------------------------------------------------
__global__ __launch_bounds__(256) void vq_loss(const double* __restrict__ partial,
                                               float*        __restrict__ losses) {
    __shared__ double sred[256];
    double v = 0.0;
#pragma unroll
    for (int i = 0; i < NPART / 256; ++i) v += partial[threadIdx.x + 256 * i];
    sred[threadIdx.x] = v;
    __syncthreads();
    for (int s = 128; s > 0; s >>= 1) {
        if (threadIdx.x < s) sred[threadIdx.x] += sred[threadIdx.x + s];
        __syncthreads();
    }
    if (threadIdx.x == 0) {
        float loss = (float)(sred[0] / (double)((size_t)NPTS * CH));
        losses[0] = loss;   // codebook_loss
        losses[1] = loss;   // commitment_loss (same value)
    }
}

// ---------------------------------------------------------------------------
extern "C" void kernel_launch(void* const* d_in, const int* in_sizes, int n_in,
                              void* d_out, int out_size, void* d_ws, size_t ws_size,
                              hipStream_t stream) {
    const float* x  = (const float*)d_in[0];   // (B, C, L)
    const float* cb = (const float*)d_in[1];   // (K, C)
    float* out = (float*)d_out;

    // d_out: [quant_out (B*C*L)] [codebook_loss] [commitment_loss] [indices (B*L)]
    float* quant_out = out;
    float* losses    = out + (size_t)BATCH * CH * LEN;
    float* idx_out   = losses + 2;

    // ws: [0,4KB) partials(512 dbl); [4KB,8KB) w2tab; [16KB,~400KB) cbf2 splits
    double* partial = (double*)d_ws;
    float*  w2tab   = (float*)((char*)d_ws + 4096);
    short*  cbf2    = (short*)((char*)d_ws + 16384);

    vq_prep<<<16, 256, 0, stream>>>(cb, cbf2, w2tab);
    vq_argmin<<<NPTS / 128, 512, 0, stream>>>(x, cb, cbf2, w2tab,
                                              quant_out, idx_out, partial);
    vq_loss<<<1, 256, 0, stream>>>(partial, losses);
}